// Round 1
// 2915.288 us; speedup vs baseline: 1.0114x; 1.0114x over previous
//
#include <hip/hip_runtime.h>
#include <stdint.h>

typedef unsigned short u16;
typedef __bf16 bf16x8 __attribute__((ext_vector_type(8)));
typedef float floatx4 __attribute__((ext_vector_type(4)));

__device__ __forceinline__ float bf2f(unsigned int u) {
    union { unsigned int i; float f; } v; v.i = u << 16; return v.f;
}
__device__ __forceinline__ u16 f2bf(float f) {
    unsigned int i = __float_as_uint(f);
    unsigned int r = (i + 0x7fffu + ((i >> 16) & 1u)) >> 16;
    return (u16)r;
}

// async global->LDS DMA, 16B per lane; LDS dest is wave-uniform base + lane*16
__device__ __forceinline__ void gload_lds16(const u16* g, u16* l) {
    __builtin_amdgcn_global_load_lds(
        (const __attribute__((address_space(1))) unsigned int*)g,
        (__attribute__((address_space(3))) unsigned int*)l, 16, 0, 0);
}

// ---------------- prep kernels ----------------

__global__ void conv_kernel(const float* __restrict__ in, u16* __restrict__ out, int n) {
    int i = (blockIdx.x * 256 + threadIdx.x) * 4;
    if (i < n) {
        const float4 v = *(const float4*)(in + i);
        uint2 o;
        o.x = (unsigned)f2bf(v.x) | ((unsigned)f2bf(v.y) << 16);
        o.y = (unsigned)f2bf(v.z) | ((unsigned)f2bf(v.w) << 16);
        *(uint2*)(out + i) = o;
    }
}

__global__ void count_kernel(const int* __restrict__ dst, int E, int* __restrict__ cnt) {
    int i = blockIdx.x * 256 + threadIdx.x;
    if (i < E) atomicAdd(&cnt[dst[i]], 1);
}

__global__ __launch_bounds__(1024)
void scan1(const int* __restrict__ cnt, int n, int* __restrict__ incl, int* __restrict__ bsum) {
    __shared__ int sh[1024];
    int tid = threadIdx.x;
    int i = blockIdx.x * 1024 + tid;
    int x = (i < n) ? cnt[i] : 0;
    sh[tid] = x; __syncthreads();
    for (int offd = 1; offd < 1024; offd <<= 1) {
        int tv = (tid >= offd) ? sh[tid - offd] : 0;
        __syncthreads();
        x += tv; sh[tid] = x;
        __syncthreads();
    }
    if (i < n) incl[i] = x;
    if (tid == 1023) bsum[blockIdx.x] = x;
}

__global__ __launch_bounds__(1024)
void scan2(int* __restrict__ bsum, int nb) {
    __shared__ int sh[1024];
    int tid = threadIdx.x;
    int v = (tid < nb) ? bsum[tid] : 0;
    int x = v;
    sh[tid] = x; __syncthreads();
    for (int offd = 1; offd < 1024; offd <<= 1) {
        int tv = (tid >= offd) ? sh[tid - offd] : 0;
        __syncthreads();
        x += tv; sh[tid] = x;
        __syncthreads();
    }
    if (tid < nb) bsum[tid] = x - v;  // exclusive
}

__global__ __launch_bounds__(1024)
void scan3(const int* __restrict__ incl, const int* __restrict__ cnt, const int* __restrict__ bsum,
           int n, int* __restrict__ rowstart, int* __restrict__ cursor, float* __restrict__ inv) {
    int i = blockIdx.x * 1024 + threadIdx.x;
    if (i < n) {
        int ex = incl[i] - cnt[i] + bsum[blockIdx.x];
        rowstart[i] = ex; cursor[i] = ex;
        inv[i] = 1.0f / fmaxf((float)cnt[i], 1.0f);
        if (i == n - 1) rowstart[n] = incl[i] + bsum[blockIdx.x];
    }
}

__global__ void scatter_kernel(const int* __restrict__ src, const int* __restrict__ dst, int E,
                               int* __restrict__ cursor, int* __restrict__ eidx) {
    int i = blockIdx.x * 256 + threadIdx.x;
    if (i < E) {
        int slot = atomicAdd(&cursor[dst[i]], 1);
        eidx[slot] = src[i];
    }
}

// stacked transposed weights: WT[n][k], k blocks = agg relations' Wl then sum of Wr
__global__ void wstack_kernel(const float* __restrict__ Wl, const float* __restrict__ Wr,
                              int layer, int r0, int r1, int r2, int nagg,
                              u16* __restrict__ WT, int Ktot) {
    int idx = blockIdx.x * 256 + threadIdx.x;
    if (idx >= 256 * Ktot) return;
    int n = idx / Ktot, k = idx - n * Ktot;
    int b = k >> 8, kk = k & 255;
    int rr[3] = {r0, r1, r2};
    float v;
    if (b < nagg) {
        v = Wl[(((size_t)layer * 7 + rr[b]) * 256 + kk) * 256 + n];
    } else {
        v = 0.0f;
        for (int j = 0; j < nagg; ++j)
            v += Wr[(((size_t)layer * 7 + rr[j]) * 256 + kk) * 256 + n];
    }
    WT[(size_t)n * Ktot + k] = f2bf(v);
}

__global__ void bstack_kernel(const float* __restrict__ bl, int layer, int r0, int r1, int r2,
                              int nagg, float* __restrict__ out) {
    int n = threadIdx.x;
    int rr[3] = {r0, r1, r2};
    float v = 0.0f;
    for (int j = 0; j < nagg; ++j) v += bl[((size_t)layer * 7 + rr[j]) * 256 + n];
    out[n] = v;
}

__global__ void woutT_kernel(const float* __restrict__ W, u16* __restrict__ WT) {
    int idx = blockIdx.x * 256 + threadIdx.x;
    if (idx < 349 * 256) {
        int n = idx / 256, k = idx - n * 256;
        WT[idx] = f2bf(W[(size_t)k * 349 + n]);
    }
}

// ---------------- aggregation: one wave per dst row ----------------

__global__ __launch_bounds__(256)
void agg_kernel(const u16* __restrict__ feat, const int* __restrict__ eidx,
                const int* __restrict__ rowstart, const float* __restrict__ inv,
                u16* __restrict__ out, int ldo, int coloff, int n_dst) {
    int w = (blockIdx.x * 256 + threadIdx.x) >> 6;
    int lane = threadIdx.x & 63;
    if (w >= n_dst) return;
    int s = rowstart[w], e = rowstart[w + 1];
    float a0 = 0, a1 = 0, a2 = 0, a3 = 0;
    for (int t = s; t < e; ++t) {
        int src = eidx[t];
        uint2 v = *(const uint2*)(feat + (size_t)src * 256 + lane * 4);
        a0 += bf2f(v.x & 0xffffu); a1 += bf2f(v.x >> 16);
        a2 += bf2f(v.y & 0xffffu); a3 += bf2f(v.y >> 16);
    }
    float iv = inv[w];
    uint2 o;
    o.x = (unsigned)f2bf(a0 * iv) | ((unsigned)f2bf(a1 * iv) << 16);
    o.y = (unsigned)f2bf(a2 * iv) | ((unsigned)f2bf(a3 * iv) << 16);
    *(uint2*)(out + (size_t)w * ldo + coloff + lane * 4) = o;
}

// ---------------- GEMM: C = act(A @ W + bias), A = [Abuf | X] bf16, MFMA ----------------
// m97 structure: global_load_lds dwordx4 staging into linear [128][32] LDS,
// single-buffered, 2 barriers per K-step. Wave w stages 16-row chunks {w, w+4}
// of both tiles; lane l covers row c*16+(l>>2), col elems (l&3)*8..+8, which is
// exactly the hardware's linear LDS dest base + l*16B (row*32+col == c*512+8l).

template <typename CT, bool RELU>
__global__ __launch_bounds__(256)
void gemm_kernel(const u16* __restrict__ A0, int lda0, int K1,
                 const u16* __restrict__ A1, int lda1, int Ktot,
                 const u16* __restrict__ WT, const float* __restrict__ bias,
                 CT* __restrict__ C, int ldc, int M, int N) {
    __shared__ u16 As[128 * 32];
    __shared__ u16 Bs[128 * 32];

    const int tid = threadIdx.x;
    const int lane = tid & 63;
    const int wid = tid >> 6;
    const int wm = (wid >> 1) * 64;
    const int wn = (wid & 1) * 64;
    const int quad = lane >> 4;
    const int l15 = lane & 15;

    const int row0 = blockIdx.x * 128;
    const int col0 = blockIdx.y * 128;

    // staging geometry
    const int c0 = wid;        // first 16-row chunk this wave stages
    const int c1 = wid + 4;    // second chunk
    const int rsub = lane >> 2;        // row within chunk (0..15)
    const int csub = (lane & 3) * 8;   // col element within 32-wide K tile

    // clamped global rows (OOB rows read row M-1 / N-1; results guarded at C-write)
    int ar0 = row0 + c0 * 16 + rsub; if (ar0 > M - 1) ar0 = M - 1;
    int ar1 = row0 + c1 * 16 + rsub; if (ar1 > M - 1) ar1 = M - 1;
    int br0 = col0 + c0 * 16 + rsub; if (br0 > N - 1) br0 = N - 1;
    int br1 = col0 + c1 * 16 + rsub; if (br1 > N - 1) br1 = N - 1;

    const u16* A0s = A0 ? A0 : A1;  // keep ptr math benign when K1==0
    const u16* a0p0 = A0s + (size_t)ar0 * lda0 + csub;
    const u16* a0p1 = A0s + (size_t)ar1 * lda0 + csub;
    const u16* a1p0 = A1 + (size_t)ar0 * lda1 + csub;
    const u16* a1p1 = A1 + (size_t)ar1 * lda1 + csub;
    const u16* bp0  = WT + (size_t)br0 * Ktot + csub;
    const u16* bp1  = WT + (size_t)br1 * Ktot + csub;

    u16* As0 = &As[c0 * 512];
    u16* As1 = &As[c1 * 512];
    u16* Bs0 = &Bs[c0 * 512];
    u16* Bs1 = &Bs[c1 * 512];

    floatx4 acc[4][4] = {};

    const int nkt = Ktot >> 5;
    for (int kt = 0; kt < nkt; ++kt) {
        const int kbase = kt * 32;
        const u16 *ga0, *ga1;
        if (kbase < K1) { ga0 = a0p0 + kbase;      ga1 = a0p1 + kbase; }
        else            { ga0 = a1p0 + kbase - K1; ga1 = a1p1 + kbase - K1; }
        gload_lds16(ga0, As0);
        gload_lds16(ga1, As1);
        gload_lds16(bp0 + kbase, Bs0);
        gload_lds16(bp1 + kbase, Bs1);
        __syncthreads();  // drains vmcnt -> staged tile visible to all waves

        bf16x8 af[4], bfr[4];
#pragma unroll
        for (int i = 0; i < 4; ++i)
            af[i] = *(const bf16x8*)&As[(wm + i * 16 + l15) * 32 + quad * 8];
#pragma unroll
        for (int j = 0; j < 4; ++j)
            bfr[j] = *(const bf16x8*)&Bs[(wn + j * 16 + l15) * 32 + quad * 8];
#pragma unroll
        for (int i = 0; i < 4; ++i)
#pragma unroll
            for (int j = 0; j < 4; ++j)
                acc[i][j] = __builtin_amdgcn_mfma_f32_16x16x32_bf16(af[i], bfr[j], acc[i][j], 0, 0, 0);
        __syncthreads();  // all waves done reading before next stage overwrites
    }

#pragma unroll
    for (int j = 0; j < 4; ++j) {
        int gn = col0 + wn + j * 16 + l15;
        float bv = (gn < N) ? bias[gn] : 0.0f;
#pragma unroll
        for (int i = 0; i < 4; ++i) {
#pragma unroll
            for (int r = 0; r < 4; ++r) {
                int gmr = row0 + wm + i * 16 + quad * 4 + r;
                if (gmr < M && gn < N) {
                    float v = acc[i][j][r] + bv;
                    if (RELU) v = fmaxf(v, 0.0f);
                    if constexpr (sizeof(CT) == 2) C[(size_t)gmr * ldc + gn] = (CT)f2bf(v);
                    else                           C[(size_t)gmr * ldc + gn] = (CT)v;
                }
            }
        }
    }
}

// ---------------- launcher ----------------

extern "C" void kernel_launch(void* const* d_in, const int* in_sizes, int n_in,
                              void* d_out, int out_size, void* d_ws, size_t ws_size,
                              hipStream_t stream) {
    const int NP = 200000, NA = 100000, NI = 8000, NF = 30000;
    const int nNodes[4] = {NP, NA, NI, NF};
    const float* xin[4] = {(const float*)d_in[0], (const float*)d_in[1],
                           (const float*)d_in[2], (const float*)d_in[3]};
    const float* Wl = (const float*)d_in[18];
    const float* bl = (const float*)d_in[19];
    const float* Wr = (const float*)d_in[20];
    const float* Wout = (const float*)d_in[21];
    const float* bout = (const float*)d_in[22];

    struct RelInfo { const int* src; const int* dst; int E; int stype; int dtype; };
    RelInfo rels[7] = {
        {(const int*)d_in[4],  (const int*)d_in[5],  500000, 0, 0},  // cites p->p
        {(const int*)d_in[6],  (const int*)d_in[7],  400000, 1, 0},  // writes a->p
        {(const int*)d_in[8],  (const int*)d_in[9],  400000, 0, 1},  // rev_writes p->a
        {(const int*)d_in[10], (const int*)d_in[11], 100000, 1, 2},  // aff a->i
        {(const int*)d_in[12], (const int*)d_in[13], 100000, 2, 1},  // rev_aff i->a
        {(const int*)d_in[14], (const int*)d_in[15], 300000, 0, 3},  // topic p->f
        {(const int*)d_in[16], (const int*)d_in[17], 300000, 3, 0},  // rev_topic f->p
    };

    char* base = (char*)d_ws;
    size_t off = 0;
    auto alloc = [&](size_t bytes) -> void* {
        void* p = base + off;
        off = (off + bytes + 255) & ~(size_t)255;
        return p;
    };

    u16* featA[4]; u16* featB[4];
    for (int t = 0; t < 4; ++t) featA[t] = (u16*)alloc((size_t)nNodes[t] * 256 * 2);
    for (int t = 0; t < 4; ++t) featB[t] = (u16*)alloc((size_t)nNodes[t] * 256 * 2);
    u16* Abuf = (u16*)alloc((size_t)NP * 768 * 2);

    int* cntR[7]; int* rsR[7]; int* curR[7]; float* invR[7]; int* eidxR[7];
    for (int r = 0; r < 7; ++r) {
        int nd = nNodes[rels[r].dtype];
        cntR[r]  = (int*)alloc((size_t)nd * 4);
        rsR[r]   = (int*)alloc((size_t)(nd + 1) * 4);
        curR[r]  = (int*)alloc((size_t)nd * 4);
        invR[r]  = (float*)alloc((size_t)nd * 4);
        eidxR[r] = (int*)alloc((size_t)rels[r].E * 4);
    }
    int* bsum = (int*)alloc(1024 * 4);
    int* incl = (int*)alloc((size_t)NP * 4);

    const int Kt[4] = {1024, 768, 512, 512};
    u16* WTl[2][4]; float* biasL[2][4];
    for (int l = 0; l < 2; ++l)
        for (int t = 0; t < 4; ++t) {
            WTl[l][t]  = (u16*)alloc((size_t)256 * Kt[t] * 2);
            biasL[l][t] = (float*)alloc(256 * 4);
        }
    u16* WoutT = (u16*)alloc((size_t)349 * 256 * 2);
    (void)ws_size; (void)in_sizes; (void)n_in; (void)out_size;

    // 1. convert inputs to bf16
    for (int t = 0; t < 4; ++t) {
        int n = nNodes[t] * 256;
        conv_kernel<<<(n / 4 + 255) / 256, 256, 0, stream>>>(xin[t], featA[t], n);
    }

    // 2. CSR per relation (reused by both layers)
    for (int r = 0; r < 7; ++r) {
        int nd = nNodes[rels[r].dtype], E = rels[r].E;
        hipMemsetAsync(cntR[r], 0, (size_t)nd * 4, stream);
        count_kernel<<<(E + 255) / 256, 256, 0, stream>>>(rels[r].dst, E, cntR[r]);
        int nb = (nd + 1023) / 1024;
        scan1<<<nb, 1024, 0, stream>>>(cntR[r], nd, incl, bsum);
        scan2<<<1, 1024, 0, stream>>>(bsum, nb);
        scan3<<<nb, 1024, 0, stream>>>(incl, cntR[r], bsum, nd, rsR[r], curR[r], invR[r]);
        scatter_kernel<<<(E + 255) / 256, 256, 0, stream>>>(rels[r].src, rels[r].dst, E,
                                                            curR[r], eidxR[r]);
    }

    // 3. stacked weights + biases
    const int relsOf[4][3] = {{0, 1, 6}, {2, 4, -1}, {3, -1, -1}, {5, -1, -1}};
    const int nAgg[4] = {3, 2, 1, 1};
    for (int l = 0; l < 2; ++l)
        for (int t = 0; t < 4; ++t) {
            int tot = 256 * Kt[t];
            wstack_kernel<<<(tot + 255) / 256, 256, 0, stream>>>(
                Wl, Wr, l, relsOf[t][0], relsOf[t][1], relsOf[t][2], nAgg[t], WTl[l][t], Kt[t]);
            bstack_kernel<<<1, 256, 0, stream>>>(bl, l, relsOf[t][0], relsOf[t][1], relsOf[t][2],
                                                 nAgg[t], biasL[l][t]);
        }
    woutT_kernel<<<(349 * 256 + 255) / 256, 256, 0, stream>>>(Wout, WoutT);

    // 4. layers
    for (int l = 0; l < 2; ++l) {
        u16** cur = (l == 0) ? featA : featB;
        u16** nxt = (l == 0) ? featB : featA;
        for (int t = 0; t < 4; ++t) {
            int K1 = Kt[t] - 256;
            int nd = nNodes[t];
            for (int b = 0; b < nAgg[t]; ++b) {
                int r = relsOf[t][b];
                agg_kernel<<<(nd + 3) / 4, 256, 0, stream>>>(
                    cur[rels[r].stype], eidxR[r], rsR[r], invR[r], Abuf, K1, b * 256, nd);
            }
            dim3 grid((nd + 127) / 128, 2);
            gemm_kernel<u16, true><<<grid, 256, 0, stream>>>(
                Abuf, K1, K1, cur[t], 256, Kt[t], WTl[l][t], biasL[l][t],
                nxt[t], 256, nd, 256);
        }
    }

    // 5. final linear: out = p @ W_out + b_out (fp32 out)
    dim3 fg((NP + 127) / 128, 3);
    gemm_kernel<float, false><<<fg, 256, 0, stream>>>(
        nullptr, 0, 0, featA[0], 256, 256, WoutT, bout, (float*)d_out, 349, NP, 349);
}

// Round 2
// 2888.171 us; speedup vs baseline: 1.0209x; 1.0094x over previous
//
#include <hip/hip_runtime.h>
#include <stdint.h>

typedef unsigned short u16;
typedef __bf16 bf16x8 __attribute__((ext_vector_type(8)));
typedef float floatx4 __attribute__((ext_vector_type(4)));

__device__ __forceinline__ float bf2f(unsigned int u) {
    union { unsigned int i; float f; } v; v.i = u << 16; return v.f;
}
__device__ __forceinline__ u16 f2bf(float f) {
    unsigned int i = __float_as_uint(f);
    unsigned int r = (i + 0x7fffu + ((i >> 16) & 1u)) >> 16;
    return (u16)r;
}

// async global->LDS DMA, 16B per lane; LDS dest is wave-uniform base + lane*16
__device__ __forceinline__ void gload_lds16(const u16* g, u16* l) {
    __builtin_amdgcn_global_load_lds(
        (const __attribute__((address_space(1))) unsigned int*)g,
        (__attribute__((address_space(3))) unsigned int*)l, 16, 0, 0);
}

// ---------------- prep kernels ----------------

__global__ void conv_kernel(const float* __restrict__ in, u16* __restrict__ out, int n) {
    int i = (blockIdx.x * 256 + threadIdx.x) * 4;
    if (i < n) {
        const float4 v = *(const float4*)(in + i);
        uint2 o;
        o.x = (unsigned)f2bf(v.x) | ((unsigned)f2bf(v.y) << 16);
        o.y = (unsigned)f2bf(v.z) | ((unsigned)f2bf(v.w) << 16);
        *(uint2*)(out + i) = o;
    }
}

__global__ void count_kernel(const int* __restrict__ dst, int E, int* __restrict__ cnt) {
    int i = blockIdx.x * 256 + threadIdx.x;
    if (i < E) atomicAdd(&cnt[dst[i]], 1);
}

__global__ __launch_bounds__(1024)
void scan1(const int* __restrict__ cnt, int n, int* __restrict__ incl, int* __restrict__ bsum) {
    __shared__ int sh[1024];
    int tid = threadIdx.x;
    int i = blockIdx.x * 1024 + tid;
    int x = (i < n) ? cnt[i] : 0;
    sh[tid] = x; __syncthreads();
    for (int offd = 1; offd < 1024; offd <<= 1) {
        int tv = (tid >= offd) ? sh[tid - offd] : 0;
        __syncthreads();
        x += tv; sh[tid] = x;
        __syncthreads();
    }
    if (i < n) incl[i] = x;
    if (tid == 1023) bsum[blockIdx.x] = x;
}

__global__ __launch_bounds__(1024)
void scan2(int* __restrict__ bsum, int nb) {
    __shared__ int sh[1024];
    int tid = threadIdx.x;
    int v = (tid < nb) ? bsum[tid] : 0;
    int x = v;
    sh[tid] = x; __syncthreads();
    for (int offd = 1; offd < 1024; offd <<= 1) {
        int tv = (tid >= offd) ? sh[tid - offd] : 0;
        __syncthreads();
        x += tv; sh[tid] = x;
        __syncthreads();
    }
    if (tid < nb) bsum[tid] = x - v;  // exclusive
}

__global__ __launch_bounds__(1024)
void scan3(const int* __restrict__ incl, const int* __restrict__ cnt, const int* __restrict__ bsum,
           int n, int* __restrict__ rowstart, int* __restrict__ cursor, float* __restrict__ inv) {
    int i = blockIdx.x * 1024 + threadIdx.x;
    if (i < n) {
        int ex = incl[i] - cnt[i] + bsum[blockIdx.x];
        rowstart[i] = ex; cursor[i] = ex;
        inv[i] = 1.0f / fmaxf((float)cnt[i], 1.0f);
        if (i == n - 1) rowstart[n] = incl[i] + bsum[blockIdx.x];
    }
}

__global__ void scatter_kernel(const int* __restrict__ src, const int* __restrict__ dst, int E,
                               int* __restrict__ cursor, int* __restrict__ eidx) {
    int i = blockIdx.x * 256 + threadIdx.x;
    if (i < E) {
        int slot = atomicAdd(&cursor[dst[i]], 1);
        eidx[slot] = src[i];
    }
}

// stacked transposed weights: WT[n][k], k blocks = agg relations' Wl then sum of Wr
__global__ void wstack_kernel(const float* __restrict__ Wl, const float* __restrict__ Wr,
                              int layer, int r0, int r1, int r2, int nagg,
                              u16* __restrict__ WT, int Ktot) {
    int idx = blockIdx.x * 256 + threadIdx.x;
    if (idx >= 256 * Ktot) return;
    int n = idx / Ktot, k = idx - n * Ktot;
    int b = k >> 8, kk = k & 255;
    int rr[3] = {r0, r1, r2};
    float v;
    if (b < nagg) {
        v = Wl[(((size_t)layer * 7 + rr[b]) * 256 + kk) * 256 + n];
    } else {
        v = 0.0f;
        for (int j = 0; j < nagg; ++j)
            v += Wr[(((size_t)layer * 7 + rr[j]) * 256 + kk) * 256 + n];
    }
    WT[(size_t)n * Ktot + k] = f2bf(v);
}

__global__ void bstack_kernel(const float* __restrict__ bl, int layer, int r0, int r1, int r2,
                              int nagg, float* __restrict__ out) {
    int n = threadIdx.x;
    int rr[3] = {r0, r1, r2};
    float v = 0.0f;
    for (int j = 0; j < nagg; ++j) v += bl[((size_t)layer * 7 + rr[j]) * 256 + n];
    out[n] = v;
}

__global__ void woutT_kernel(const float* __restrict__ W, u16* __restrict__ WT) {
    int idx = blockIdx.x * 256 + threadIdx.x;
    if (idx < 349 * 256) {
        int n = idx / 256, k = idx - n * 256;
        WT[idx] = f2bf(W[(size_t)k * 349 + n]);
    }
}

// ---------------- aggregation: one wave per dst row ----------------

__global__ __launch_bounds__(256)
void agg_kernel(const u16* __restrict__ feat, const int* __restrict__ eidx,
                const int* __restrict__ rowstart, const float* __restrict__ inv,
                u16* __restrict__ out, int ldo, int coloff, int n_dst) {
    int w = (blockIdx.x * 256 + threadIdx.x) >> 6;
    int lane = threadIdx.x & 63;
    if (w >= n_dst) return;
    int s = rowstart[w], e = rowstart[w + 1];
    float a0 = 0, a1 = 0, a2 = 0, a3 = 0;
    for (int t = s; t < e; ++t) {
        int src = eidx[t];
        uint2 v = *(const uint2*)(feat + (size_t)src * 256 + lane * 4);
        a0 += bf2f(v.x & 0xffffu); a1 += bf2f(v.x >> 16);
        a2 += bf2f(v.y & 0xffffu); a3 += bf2f(v.y >> 16);
    }
    float iv = inv[w];
    uint2 o;
    o.x = (unsigned)f2bf(a0 * iv) | ((unsigned)f2bf(a1 * iv) << 16);
    o.y = (unsigned)f2bf(a2 * iv) | ((unsigned)f2bf(a3 * iv) << 16);
    *(uint2*)(out + (size_t)w * ldo + coloff + lane * 4) = o;
}

// ---------------- GEMM: C = act(A @ W + bias), A = [Abuf | X] bf16, MFMA ----------------
// 2-phase double-buffered (T3 minimum recipe): issue next K-tile's global_load_lds
// BEFORE reading/computing the current tile; single __syncthreads per K-step at the
// end (its vmcnt(0) waits on loads that flew during the whole compute phase).
// Staging: wave w DMAs 16-row chunks {w, w+4}; lane l covers row c*16+(l>>2),
// cols (l&3)*8 -> exactly linear LDS dest base + l*16B (row*32+col == c*512+8l).

template <typename CT, bool RELU>
__global__ __launch_bounds__(256)
void gemm_kernel(const u16* __restrict__ A0, int lda0, int K1,
                 const u16* __restrict__ A1, int lda1, int Ktot,
                 const u16* __restrict__ WT, const float* __restrict__ bias,
                 CT* __restrict__ C, int ldc, int M, int N) {
    __shared__ u16 As[2][128 * 32];
    __shared__ u16 Bs[2][128 * 32];

    const int tid = threadIdx.x;
    const int lane = tid & 63;
    const int wid = tid >> 6;
    const int wm = (wid >> 1) * 64;
    const int wn = (wid & 1) * 64;
    const int quad = lane >> 4;
    const int l15 = lane & 15;

    const int row0 = blockIdx.x * 128;
    const int col0 = blockIdx.y * 128;

    // staging geometry
    const int c0 = wid;        // first 16-row chunk this wave stages
    const int c1 = wid + 4;    // second chunk
    const int rsub = lane >> 2;        // row within chunk (0..15)
    const int csub = (lane & 3) * 8;   // col element within 32-wide K tile

    // clamped global rows (OOB rows read row M-1 / N-1; results guarded at C-write)
    int ar0 = row0 + c0 * 16 + rsub; if (ar0 > M - 1) ar0 = M - 1;
    int ar1 = row0 + c1 * 16 + rsub; if (ar1 > M - 1) ar1 = M - 1;
    int br0 = col0 + c0 * 16 + rsub; if (br0 > N - 1) br0 = N - 1;
    int br1 = col0 + c1 * 16 + rsub; if (br1 > N - 1) br1 = N - 1;

    const u16* A0s = A0 ? A0 : A1;  // keep ptr math benign when K1==0
    const u16* a0p0 = A0s + (size_t)ar0 * lda0 + csub;
    const u16* a0p1 = A0s + (size_t)ar1 * lda0 + csub;
    const u16* a1p0 = A1 + (size_t)ar0 * lda1 + csub;
    const u16* a1p1 = A1 + (size_t)ar1 * lda1 + csub;
    const u16* bp0  = WT + (size_t)br0 * Ktot + csub;
    const u16* bp1  = WT + (size_t)br1 * Ktot + csub;

    floatx4 acc[4][4] = {};

    auto STAGE = [&](int b, int kt) {
        const int kbase = kt * 32;
        const u16 *ga0, *ga1;
        if (kbase < K1) { ga0 = a0p0 + kbase;      ga1 = a0p1 + kbase; }
        else            { ga0 = a1p0 + kbase - K1; ga1 = a1p1 + kbase - K1; }
        gload_lds16(ga0, &As[b][c0 * 512]);
        gload_lds16(ga1, &As[b][c1 * 512]);
        gload_lds16(bp0 + kbase, &Bs[b][c0 * 512]);
        gload_lds16(bp1 + kbase, &Bs[b][c1 * 512]);
    };

    auto COMPUTE = [&](int b) {
        bf16x8 af[4], bfr[4];
#pragma unroll
        for (int i = 0; i < 4; ++i)
            af[i] = *(const bf16x8*)&As[b][(wm + i * 16 + l15) * 32 + quad * 8];
#pragma unroll
        for (int j = 0; j < 4; ++j)
            bfr[j] = *(const bf16x8*)&Bs[b][(wn + j * 16 + l15) * 32 + quad * 8];
#pragma unroll
        for (int i = 0; i < 4; ++i)
#pragma unroll
            for (int j = 0; j < 4; ++j)
                acc[i][j] = __builtin_amdgcn_mfma_f32_16x16x32_bf16(af[i], bfr[j], acc[i][j], 0, 0, 0);
    };

    const int nkt = Ktot >> 5;
    // prologue: fill buffer 0 with tile 0
    STAGE(0, 0);
    __syncthreads();  // vmcnt(0) + barrier: tile 0 resident
    for (int kt = 0; kt < nkt - 1; ++kt) {
        STAGE((kt + 1) & 1, kt + 1);  // issue next tile's DMAs first
        COMPUTE(kt & 1);              // compute current tile (overlaps DMA flight)
        __syncthreads();              // vmcnt(0): next tile landed; reads of cur done
    }
    COMPUTE((nkt - 1) & 1);           // epilogue: last tile, no prefetch

#pragma unroll
    for (int j = 0; j < 4; ++j) {
        int gn = col0 + wn + j * 16 + l15;
        float bv = (gn < N) ? bias[gn] : 0.0f;
#pragma unroll
        for (int i = 0; i < 4; ++i) {
#pragma unroll
            for (int r = 0; r < 4; ++r) {
                int gmr = row0 + wm + i * 16 + quad * 4 + r;
                if (gmr < M && gn < N) {
                    float v = acc[i][j][r] + bv;
                    if (RELU) v = fmaxf(v, 0.0f);
                    if constexpr (sizeof(CT) == 2) C[(size_t)gmr * ldc + gn] = (CT)f2bf(v);
                    else                           C[(size_t)gmr * ldc + gn] = (CT)v;
                }
            }
        }
    }
}

// ---------------- launcher ----------------

extern "C" void kernel_launch(void* const* d_in, const int* in_sizes, int n_in,
                              void* d_out, int out_size, void* d_ws, size_t ws_size,
                              hipStream_t stream) {
    const int NP = 200000, NA = 100000, NI = 8000, NF = 30000;
    const int nNodes[4] = {NP, NA, NI, NF};
    const float* xin[4] = {(const float*)d_in[0], (const float*)d_in[1],
                           (const float*)d_in[2], (const float*)d_in[3]};
    const float* Wl = (const float*)d_in[18];
    const float* bl = (const float*)d_in[19];
    const float* Wr = (const float*)d_in[20];
    const float* Wout = (const float*)d_in[21];
    const float* bout = (const float*)d_in[22];

    struct RelInfo { const int* src; const int* dst; int E; int stype; int dtype; };
    RelInfo rels[7] = {
        {(const int*)d_in[4],  (const int*)d_in[5],  500000, 0, 0},  // cites p->p
        {(const int*)d_in[6],  (const int*)d_in[7],  400000, 1, 0},  // writes a->p
        {(const int*)d_in[8],  (const int*)d_in[9],  400000, 0, 1},  // rev_writes p->a
        {(const int*)d_in[10], (const int*)d_in[11], 100000, 1, 2},  // aff a->i
        {(const int*)d_in[12], (const int*)d_in[13], 100000, 2, 1},  // rev_aff i->a
        {(const int*)d_in[14], (const int*)d_in[15], 300000, 0, 3},  // topic p->f
        {(const int*)d_in[16], (const int*)d_in[17], 300000, 3, 0},  // rev_topic f->p
    };

    char* base = (char*)d_ws;
    size_t off = 0;
    auto alloc = [&](size_t bytes) -> void* {
        void* p = base + off;
        off = (off + bytes + 255) & ~(size_t)255;
        return p;
    };

    u16* featA[4]; u16* featB[4];
    for (int t = 0; t < 4; ++t) featA[t] = (u16*)alloc((size_t)nNodes[t] * 256 * 2);
    for (int t = 0; t < 4; ++t) featB[t] = (u16*)alloc((size_t)nNodes[t] * 256 * 2);
    u16* Abuf = (u16*)alloc((size_t)NP * 768 * 2);

    int* cntR[7]; int* rsR[7]; int* curR[7]; float* invR[7]; int* eidxR[7];
    for (int r = 0; r < 7; ++r) {
        int nd = nNodes[rels[r].dtype];
        cntR[r]  = (int*)alloc((size_t)nd * 4);
        rsR[r]   = (int*)alloc((size_t)(nd + 1) * 4);
        curR[r]  = (int*)alloc((size_t)nd * 4);
        invR[r]  = (float*)alloc((size_t)nd * 4);
        eidxR[r] = (int*)alloc((size_t)rels[r].E * 4);
    }
    int* bsum = (int*)alloc(1024 * 4);
    int* incl = (int*)alloc((size_t)NP * 4);

    const int Kt[4] = {1024, 768, 512, 512};
    u16* WTl[2][4]; float* biasL[2][4];
    for (int l = 0; l < 2; ++l)
        for (int t = 0; t < 4; ++t) {
            WTl[l][t]  = (u16*)alloc((size_t)256 * Kt[t] * 2);
            biasL[l][t] = (float*)alloc(256 * 4);
        }
    u16* WoutT = (u16*)alloc((size_t)349 * 256 * 2);
    (void)ws_size; (void)in_sizes; (void)n_in; (void)out_size;

    // 1. convert inputs to bf16
    for (int t = 0; t < 4; ++t) {
        int n = nNodes[t] * 256;
        conv_kernel<<<(n / 4 + 255) / 256, 256, 0, stream>>>(xin[t], featA[t], n);
    }

    // 2. CSR per relation (reused by both layers)
    for (int r = 0; r < 7; ++r) {
        int nd = nNodes[rels[r].dtype], E = rels[r].E;
        hipMemsetAsync(cntR[r], 0, (size_t)nd * 4, stream);
        count_kernel<<<(E + 255) / 256, 256, 0, stream>>>(rels[r].dst, E, cntR[r]);
        int nb = (nd + 1023) / 1024;
        scan1<<<nb, 1024, 0, stream>>>(cntR[r], nd, incl, bsum);
        scan2<<<1, 1024, 0, stream>>>(bsum, nb);
        scan3<<<nb, 1024, 0, stream>>>(incl, cntR[r], bsum, nd, rsR[r], curR[r], invR[r]);
        scatter_kernel<<<(E + 255) / 256, 256, 0, stream>>>(rels[r].src, rels[r].dst, E,
                                                            curR[r], eidxR[r]);
    }

    // 3. stacked weights + biases
    const int relsOf[4][3] = {{0, 1, 6}, {2, 4, -1}, {3, -1, -1}, {5, -1, -1}};
    const int nAgg[4] = {3, 2, 1, 1};
    for (int l = 0; l < 2; ++l)
        for (int t = 0; t < 4; ++t) {
            int tot = 256 * Kt[t];
            wstack_kernel<<<(tot + 255) / 256, 256, 0, stream>>>(
                Wl, Wr, l, relsOf[t][0], relsOf[t][1], relsOf[t][2], nAgg[t], WTl[l][t], Kt[t]);
            bstack_kernel<<<1, 256, 0, stream>>>(bl, l, relsOf[t][0], relsOf[t][1], relsOf[t][2],
                                                 nAgg[t], biasL[l][t]);
        }
    woutT_kernel<<<(349 * 256 + 255) / 256, 256, 0, stream>>>(Wout, WoutT);

    // 4. layers
    for (int l = 0; l < 2; ++l) {
        u16** cur = (l == 0) ? featA : featB;
        u16** nxt = (l == 0) ? featB : featA;
        for (int t = 0; t < 4; ++t) {
            int K1 = Kt[t] - 256;
            int nd = nNodes[t];
            for (int b = 0; b < nAgg[t]; ++b) {
                int r = relsOf[t][b];
                agg_kernel<<<(nd + 3) / 4, 256, 0, stream>>>(
                    cur[rels[r].stype], eidxR[r], rsR[r], invR[r], Abuf, K1, b * 256, nd);
            }
            dim3 grid((nd + 127) / 128, 2);
            gemm_kernel<u16, true><<<grid, 256, 0, stream>>>(
                Abuf, K1, K1, cur[t], 256, Kt[t], WTl[l][t], biasL[l][t],
                nxt[t], 256, nd, 256);
        }
    }

    // 5. final linear: out = p @ W_out + b_out (fp32 out)
    dim3 fg((NP + 127) / 128, 3);
    gemm_kernel<float, false><<<fg, 256, 0, stream>>>(
        nullptr, 0, 0, featA[0], 256, 256, WoutT, bout, (float*)d_out, 349, NP, 349);
}